// Round 12
// baseline (4354.065 us; speedup 1.0000x reference)
//
#include <hip/hip_runtime.h>
#include <hip/hip_bf16.h>
#include <math.h>

#define B_ 1024
#define T_ 128
#define D_ 13
#define H_ 512
#define C_ 9
#define TC_ 32              /* time chunk */
#define NC_ (T_/TC_)        /* 4 chunks */
#define NT_ (B_*T_)         /* 131072 */
#define EPS 1e-5f
#define WPAD 520            /* padded hbd row stride (shorts): 1040B -> 4-bank shift/row */

using frag_ab = __attribute__((ext_vector_type(8))) short;   // 8 bf16 (4 VGPRs)
using frag_cd = __attribute__((ext_vector_type(4))) float;   // 4 fp32
typedef unsigned short ushort8 __attribute__((ext_vector_type(8)));

static __device__ __forceinline__ float bf2f(unsigned short u){
  union { unsigned int i; float f; } v; v.i = ((unsigned int)u)<<16; return v.f;
}
static __device__ __forceinline__ unsigned short f2bf(float f){
  union { float f; unsigned int i; } v; v.f = f;
  unsigned int r = v.i + 0x7FFF + ((v.i >> 16) & 1);   // round-to-nearest-even
  return (unsigned short)(r >> 16);
}
static __device__ __forceinline__ float sigmoidf_(float x){ return 1.0f/(1.0f+__expf(-x)); }
static __device__ __forceinline__ float tanhf_(float x){
  return 1.0f - 2.0f/(__expf(2.0f*x)+1.0f);   // saturates via exp over/underflow
}

__global__ void k_zero(unsigned int* __restrict__ p, int n){
  int i=blockIdx.x*256+threadIdx.x; if(i<n) p[i]=0u;
}

// ---- swizzle WhK (fp32 512x512) into per-(64-col-slice) contiguous MFMA B-fragment stream ----
// dst = w*32768 + (kc*4+c)*512 + lane*8 + e <- W[row=w*64+c*16+(lane&15)][col=kc*32+(lane>>4)*8+e]
__global__ void k_swz(const float* __restrict__ Wf, unsigned short* __restrict__ Wz){
  int dst = blockIdx.x*256 + threadIdx.x;   // over 512*512
  int w = dst >> 15;
  int i = (dst >> 9) & 63;
  int L = (dst >> 3) & 63;
  int e = dst & 7;
  int kc = i >> 2, c = i & 3;
  int row = w*64 + c*16 + (L & 15);
  int col = kc*32 + ((L >> 4) << 3) + e;
  Wz[dst] = f2bf(Wf[row*H_ + col]);
}

// ---------------- input LN + layer-1 projections (K=13, VALU), one chunk ----------------
__global__ __launch_bounds__(256) void k_proj1(
    const float* __restrict__ x, const float* __restrict__ g, const float* __restrict__ bvec,
    const float* __restrict__ WxK, const float* __restrict__ bxK,
    const float* __restrict__ Wxz, const float* __restrict__ bxz,
    unsigned short* __restrict__ xKo, unsigned short* __restrict__ zo, int t0)
{
  __shared__ float wK[H_*D_];     // 26KB
  __shared__ float wz[H_*D_];     // 26KB
  __shared__ float xn[TC_][D_];   // 1.7KB
  int tid = threadIdx.x;
  int b = blockIdx.x;             // one batch row per block, TC_ timesteps
  const float* xin = x + ((size_t)b*T_ + t0)*D_;
  for(int i=tid;i<H_*D_;i+=256){ wK[i]=WxK[i]; wz[i]=Wxz[i]; }
  for(int i=tid;i<TC_*D_;i+=256){ ((float*)xn)[i] = xin[i]; }
  __syncthreads();
  if(tid<TC_){
    float m=0.f; for(int d=0;d<D_;++d) m+=xn[tid][d]; m*=(1.0f/D_);
    float v=0.f; for(int d=0;d<D_;++d){float t=xn[tid][d]-m; v+=t*t;} v*=(1.0f/D_);
    float inv = rsqrtf(v+EPS);
    for(int d=0;d<D_;++d) xn[tid][d] = (xn[tid][d]-m)*inv*g[d]+bvec[d];
  }
  __syncthreads();
  size_t ob = (size_t)b*TC_*H_;   // chunk-local (B, TC, H)
  for(int hh=0; hh<2; ++hh){
    int h = tid + hh*256;
    float bK = bxK[h], bz = bxz[h];
    for(int r=0;r<TC_;++r){
      float aK=bK, az=bz;
      #pragma unroll
      for(int d=0;d<D_;++d){ float xv = xn[r][d]; aK += xv*wK[h*D_+d]; az += xv*wz[h*D_+d]; }
      xKo[ob + (size_t)r*H_ + h] = f2bf(aK);
      zo [ob + (size_t)r*H_ + h] = f2bf(tanhf_(az));
    }
  }
}

// ---- recurrence v9: 8 waves, 256-VGPR budget, 3-phase streamed-weight prefetch ----
// r11 evidence: VGPR=64 starved memory-level parallelism (load->stall->MFMA lockstep).
// Here: 512 thr -> 1 block/CU (153KB LDS) -> exactly 2 waves/SIMD; amdgpu_waves_per_eu(2,2)
// pins the allocator to the 256-VGPR budget. Streamed frags f15..63 prefetched in 3 explicit
// phases (17/16/16 frags) so ~16 loads are in flight 4 kc-groups ahead of use.
// Dual padded hbd + single end-of-step barrier (r11-validated). BN stats fused.
__global__ __launch_bounds__(512) __attribute__((amdgpu_waves_per_eu(2,2))) void k_recur9(
    const unsigned short* __restrict__ xK, const unsigned short* __restrict__ z, // (B,TC,H)
    const unsigned short* __restrict__ Wz,   // swizzled weights, 512KB
    const float* __restrict__ bhK,
    unsigned short* __restrict__ o,          // full (B,T,H)
    float* __restrict__ hbuf,                // (B,H) fp32 carry
    float* __restrict__ stats, int t0)       // [sum(512)|sumsq(512)] for this layer
{
  __shared__ __align__(16) unsigned short Wl[8*15*512];    // 120KB: f0..14 per wave
  __shared__ __align__(16) unsigned short hbd[2][16*WPAD]; // 33.3KB dual h buffers (padded)
  int tid=threadIdx.x, lane=tid&63, w=tid>>6;
  int q=lane>>4, cl=lane&15;
  int b0 = blockIdx.x*16;
  const unsigned short* wb = Wz + ((size_t)w<<15);   // this wave's 64KB slice
  const unsigned short* wl = Wl + w*7680;            // its resident f0..14
  // stage Wl: 7680 ushort8 chunks (960 per wave-slice)
  for(int j=tid;j<7680;j+=512){
    int wv = j/960, off8 = j%960;
    *(ushort8*)&Wl[wv*7680 + off8*8] = *(const ushort8*)&Wz[((size_t)wv<<15) + off8*8];
  }
  float hp[16];                  // [c*4+rg] own h fp32
  float bh[4]; int col[4];
  float ss[4]={0.f,0.f,0.f,0.f}, qq[4]={0.f,0.f,0.f,0.f};   // BN partial sums per c
  #pragma unroll
  for(int c=0;c<4;++c){ col[c]=w*64 + c*16 + cl; bh[c]=bhK[col[c]]; }
  if(t0==0){
    for(int i=tid;i<16*WPAD;i+=512) hbd[0][i]=0;
    #pragma unroll
    for(int i=0;i<16;++i) hp[i]=0.f;
  } else {
    for(int i=tid;i<16*H_;i+=512){ int r=i>>9,c=i&511; hbd[0][r*WPAD+c]=f2bf(hbuf[(size_t)(b0+r)*H_+c]); }
    #pragma unroll
    for(int c=0;c<4;++c)
      #pragma unroll
      for(int rg=0;rg<4;++rg) hp[c*4+rg]=hbuf[(size_t)(b0+q*4+rg)*H_+col[c]];
  }
  __syncthreads();   // Wl + hbd[0] ready
  for(int dt=0;dt<TC_;++dt){
    int cb = dt&1, nb = cb^1;
    // gate inputs for this step (issued first; consumed in epilogue, covered by MFMA phase)
    float ga[16], za[16];
    #pragma unroll
    for(int c=0;c<4;++c)
      #pragma unroll
      for(int rg=0;rg<4;++rg){
        size_t gi = ((size_t)(b0+q*4+rg)*TC_ + dt)*H_ + col[c];
        ga[c*4+rg]=bf2f(xK[gi]); za[c*4+rg]=bf2f(z[gi]);
      }
    frag_cd acc[4] = {};
    // phase A prefetch: f15..31 (17 frags, 68 VGPR)
    frag_ab wr1[17];
    #pragma unroll
    for(int f=0;f<17;++f) wr1[f] = *(const frag_ab*)&wb[(15+f)*512 + lane*8];
    // kc 0..3 uses f0..15 (f0..14 LDS, f15 = wr1[0])
    #pragma unroll
    for(int kc=0;kc<4;++kc){
      frag_ab af = *(const frag_ab*)&hbd[cb][cl*WPAD + kc*32 + q*8];
      #pragma unroll
      for(int c=0;c<4;++c){
        int f = kc*4+c;
        frag_ab bf = (f<15) ? *(const frag_ab*)&wl[f*512 + lane*8] : wr1[0];
        acc[c] = __builtin_amdgcn_mfma_f32_16x16x32_bf16(af, bf, acc[c], 0,0,0);
      }
    }
    // phase B prefetch: f32..47 (16 frags) — in flight during kc 4..7
    frag_ab wr2[16];
    #pragma unroll
    for(int f=0;f<16;++f) wr2[f] = *(const frag_ab*)&wb[(32+f)*512 + lane*8];
    #pragma unroll
    for(int kc=4;kc<8;++kc){
      frag_ab af = *(const frag_ab*)&hbd[cb][cl*WPAD + kc*32 + q*8];
      #pragma unroll
      for(int c=0;c<4;++c)
        acc[c] = __builtin_amdgcn_mfma_f32_16x16x32_bf16(af, wr1[kc*4+c-15], acc[c], 0,0,0);
    }
    // phase C prefetch: f48..63 (16 frags) — in flight during kc 8..11
    frag_ab wr3[16];
    #pragma unroll
    for(int f=0;f<16;++f) wr3[f] = *(const frag_ab*)&wb[(48+f)*512 + lane*8];
    #pragma unroll
    for(int kc=8;kc<12;++kc){
      frag_ab af = *(const frag_ab*)&hbd[cb][cl*WPAD + kc*32 + q*8];
      #pragma unroll
      for(int c=0;c<4;++c)
        acc[c] = __builtin_amdgcn_mfma_f32_16x16x32_bf16(af, wr2[kc*4+c-32], acc[c], 0,0,0);
    }
    #pragma unroll
    for(int kc=12;kc<16;++kc){
      frag_ab af = *(const frag_ab*)&hbd[cb][cl*WPAD + kc*32 + q*8];
      #pragma unroll
      for(int c=0;c<4;++c)
        acc[c] = __builtin_amdgcn_mfma_f32_16x16x32_bf16(af, wr3[kc*4+c-48], acc[c], 0,0,0);
    }
    // epilogue: gates, write h(dt) into hbd[nb]
    unsigned short hnb[16];
    #pragma unroll
    for(int c=0;c<4;++c){
      #pragma unroll
      for(int rg=0;rg<4;++rg){
        int idx = c*4+rg;
        float gv = acc[c][rg] + bh[c] + ga[idx];
        float K  = sigmoidf_(gv);
        float hn = tanhf_(K*hp[idx] + (1.f-K)*za[idx]);
        hp[idx]=hn;
        hnb[idx]=f2bf(hn);
        hbd[nb][(q*4+rg)*WPAD + col[c]] = hnb[idx];
        float hf = bf2f(hnb[idx]);       // stats on bf16-rounded value (matches reference path)
        ss[c] += hf; qq[c] += hf*hf;
      }
    }
    __syncthreads();   // single barrier: hbd[nb] visible; prior reads of hbd[cb] drained
    // o-stores after the barrier: outstanding during next MFMA phase
    #pragma unroll
    for(int c=0;c<4;++c)
      #pragma unroll
      for(int rg=0;rg<4;++rg)
        o[((size_t)(b0+q*4+rg)*T_ + t0+dt)*H_ + col[c]] = hnb[c*4+rg];
  }
  #pragma unroll
  for(int c=0;c<4;++c)
    #pragma unroll
    for(int rg=0;rg<4;++rg) hbuf[(size_t)(b0+q*4+rg)*H_+col[c]] = hp[c*4+rg];
  // fused BN stats: reduce over q (lanes 16 apart), one atomic per (col, block)
  #pragma unroll
  for(int c=0;c<4;++c){
    float s=ss[c], sq=qq[c];
    s  += __shfl_xor(s,16,64);  s  += __shfl_xor(s,32,64);
    sq += __shfl_xor(sq,16,64); sq += __shfl_xor(sq,32,64);
    if(q==0){ atomicAdd(&stats[col[c]], s); atomicAdd(&stats[H_+col[c]], sq); }
  }
}

// ---------------- fold BN into projection weights / bias ----------------
__global__ void k_foldw(const float* __restrict__ WxK, const float* __restrict__ Wxz,
                        const float* __restrict__ stats, const float* __restrict__ bng,
                        unsigned short* __restrict__ Wp){
  int i = blockIdx.x*256+threadIdx.x;           // over 1024*512
  int n = i>>9, k = i&511;
  float mean = stats[k]*(1.f/NT_);
  float var  = stats[H_+k]*(1.f/NT_) - mean*mean;
  float s = bng[k]*rsqrtf(var+EPS);
  float wv = (n<H_) ? WxK[(size_t)n*H_+k] : Wxz[(size_t)(n-H_)*H_+k];
  Wp[i] = f2bf(wv*s);
}

__global__ __launch_bounds__(256) void k_foldb(const float* __restrict__ WxK, const float* __restrict__ Wxz,
                        const float* __restrict__ stats, const float* __restrict__ bng, const float* __restrict__ bnb,
                        const float* __restrict__ bxK, const float* __restrict__ bxz,
                        float* __restrict__ biasp){
  int w = threadIdx.x>>6, lane=threadIdx.x&63;
  int n = blockIdx.x*4 + w;
  const float* W = (n<H_) ? &WxK[(size_t)n*H_] : &Wxz[(size_t)(n-H_)*H_];
  float base = (n<H_) ? bxK[n] : bxz[n-H_];
  float acc=0.f;
  for(int k=lane;k<H_;k+=64){
    float mean = stats[k]*(1.f/NT_);
    float var  = stats[H_+k]*(1.f/NT_)-mean*mean;
    float s = bng[k]*rsqrtf(var+EPS);
    float t = bnb[k]-mean*s;
    acc += t*W[k];
  }
  for(int off=32;off;off>>=1) acc += __shfl_down(acc, off, 64);
  if(lane==0) biasp[n] = base + acc;
}

// ------- layers 2/3 projections, one chunk: 128x128 bf16 MFMA GEMM, N=1024=[xK|z] -------
__global__ __launch_bounds__(256) void k_proj23(
    const unsigned short* __restrict__ A,    // full o (B,T,H) bf16
    const unsigned short* __restrict__ Wp,   // (1024, 512) bf16 folded
    const float* __restrict__ biasp,         // 1024
    unsigned short* __restrict__ xKo, unsigned short* __restrict__ zo, int t0) // (B,TC,H)
{
  __shared__ __align__(16) unsigned short As[128*32];
  __shared__ __align__(16) unsigned short Bs[128*32];
  int tid=threadIdx.x, lane=tid&63, w=tid>>6;
  int q=lane>>4, cl=lane&15;
  int b0p = blockIdx.x*4;           // 4 batch rows x 32 timesteps = 128 M-rows
  int n0 = blockIdx.y*128;
  int wm = (w>>1)*64, wn=(w&1)*64;
  frag_cd acc[4][4] = {};
  int sr = tid>>1, cb = (tid&1)*16;
  size_t arow = ((size_t)(b0p + (sr>>5))*T_ + t0 + (sr&31))*H_;
  size_t brow = (size_t)(n0+sr)*H_;
  for(int k0=0;k0<H_;k0+=32){
    *(frag_ab*)&As[sr*32+cb]   = *(const frag_ab*)&A [arow + k0+cb];
    *(frag_ab*)&As[sr*32+cb+8] = *(const frag_ab*)&A [arow + k0+cb+8];
    *(frag_ab*)&Bs[sr*32+cb]   = *(const frag_ab*)&Wp[brow + k0+cb];
    *(frag_ab*)&Bs[sr*32+cb+8] = *(const frag_ab*)&Wp[brow + k0+cb+8];
    __syncthreads();
    frag_ab af[4], bfr[4];
    #pragma unroll
    for(int mt=0;mt<4;++mt) af[mt]  = *(const frag_ab*)&As[(wm+mt*16+cl)*32 + q*8];
    #pragma unroll
    for(int nt=0;nt<4;++nt) bfr[nt] = *(const frag_ab*)&Bs[(wn+nt*16+cl)*32 + q*8];
    #pragma unroll
    for(int mt=0;mt<4;++mt)
      #pragma unroll
      for(int nt=0;nt<4;++nt)
        acc[mt][nt] = __builtin_amdgcn_mfma_f32_16x16x32_bf16(af[mt], bfr[nt], acc[mt][nt],0,0,0);
    __syncthreads();
  }
  #pragma unroll
  for(int nt=0;nt<4;++nt){
    int coln = n0+wn+nt*16+cl;
    float bp = biasp[coln];
    bool isz = coln>=H_;
    #pragma unroll
    for(int mt=0;mt<4;++mt){
      #pragma unroll
      for(int rg=0;rg<4;++rg){
        int rm = wm+mt*16+q*4+rg;                       // chunk-local row
        size_t orow = (size_t)(b0p*TC_ + rm)*H_;
        float v = acc[mt][nt][rg] + bp;
        if(isz) zo [orow + coln-H_] = f2bf(tanhf_(v));
        else    xKo[orow + coln]    = f2bf(v);
      }
    }
  }
}

// ---------------- head: BN3 + LN + 512->9 GEMV + log_softmax ----------------
__global__ __launch_bounds__(512) void k_head(const unsigned short* __restrict__ o,
     const float* __restrict__ stats, const float* __restrict__ bng, const float* __restrict__ bnb,
     const float* __restrict__ clng, const float* __restrict__ clnb,
     const float* __restrict__ Wc, const float* __restrict__ bc, float* __restrict__ out)
{
  __shared__ float red[8];
  __shared__ float lred[8][9];
  int tid=threadIdx.x, lane=tid&63, w=tid>>6;
  int b = blockIdx.x;
  int c = tid;
  float v = bf2f(o[((size_t)b*T_ + (T_-1))*H_ + c]);
  float mean = stats[c]*(1.f/NT_), var = stats[H_+c]*(1.f/NT_)-mean*mean;
  float s = bng[c]*rsqrtf(var+EPS);
  float y = v*s + (bnb[c]-mean*s);
  float sm=y;
  for(int off=32;off;off>>=1) sm+=__shfl_down(sm,off,64);
  if(lane==0) red[w]=sm;
  __syncthreads();
  float mu=0.f; for(int i=0;i<8;++i) mu+=red[i]; mu*=(1.f/H_);
  float d = y-mu;
  float vq = d*d;
  for(int off=32;off;off>>=1) vq+=__shfl_down(vq,off,64);
  __syncthreads();
  if(lane==0) red[w]=vq;
  __syncthreads();
  float vv=0.f; for(int i=0;i<8;++i) vv+=red[i]; vv*=(1.f/H_);
  float yn = d*rsqrtf(vv+EPS)*clng[c]+clnb[c];
  for(int cls=0;cls<C_;++cls){
    float t = yn*Wc[(size_t)cls*H_+c];
    for(int off=32;off;off>>=1) t+=__shfl_down(t,off,64);
    if(lane==0) lred[w][cls]=t;
  }
  __syncthreads();
  if(tid==0){
    float lg[C_]; float mx=-1e30f;
    for(int cls=0;cls<C_;++cls){
      float t=bc[cls]; for(int i=0;i<8;++i) t+=lred[i][cls];
      lg[cls]=t; mx=fmaxf(mx,t);
    }
    float se=0.f; for(int cls=0;cls<C_;++cls) se+=__expf(lg[cls]-mx);
    float lse=mx+logf(se);
    for(int cls=0;cls<C_;++cls) out[(size_t)b*C_+cls]=lg[cls]-lse;
  }
}

extern "C" void kernel_launch(void* const* d_in, const int* in_sizes, int n_in,
                              void* d_out, int out_size, void* d_ws, size_t ws_size,
                              hipStream_t stream)
{
  (void)in_sizes; (void)n_in; (void)out_size; (void)ws_size;
  const float* x    =(const float*)d_in[0];
  const float* inlng=(const float*)d_in[1];
  const float* inlnb=(const float*)d_in[2];
  const float* WxK1 =(const float*)d_in[3];
  const float* bxK1 =(const float*)d_in[4];
  const float* Wxz1 =(const float*)d_in[5];
  const float* bxz1 =(const float*)d_in[6];
  const float* WhK1 =(const float*)d_in[7];
  const float* bhK1 =(const float*)d_in[8];
  const float* bn1g =(const float*)d_in[9];
  const float* bn1b =(const float*)d_in[10];
  const float* WxK2 =(const float*)d_in[11];
  const float* bxK2 =(const float*)d_in[12];
  const float* Wxz2 =(const float*)d_in[13];
  const float* bxz2 =(const float*)d_in[14];
  const float* WhK2 =(const float*)d_in[15];
  const float* bhK2 =(const float*)d_in[16];
  const float* bn2g =(const float*)d_in[17];
  const float* bn2b =(const float*)d_in[18];
  const float* clng =(const float*)d_in[19];
  const float* clnb =(const float*)d_in[20];
  const float* Wc   =(const float*)d_in[21];
  const float* bc   =(const float*)d_in[22];
  float* out=(float*)d_out;

  // workspace carve: ~196 MiB
  char* p=(char*)d_ws;
  unsigned short* o   =(unsigned short*)p; p+=(size_t)NT_*H_*2;        // 128 MiB
  unsigned short* xK  =(unsigned short*)p; p+=(size_t)B_*TC_*H_*2;     // 32 MiB (one chunk)
  unsigned short* z   =(unsigned short*)p; p+=(size_t)B_*TC_*H_*2;     // 32 MiB
  float* hbuf         =(float*)p;          p+=(size_t)B_*H_*4;         // 2 MiB
  unsigned short* Wz1 =(unsigned short*)p; p+=(size_t)H_*H_*2;         // 0.5 MiB (swizzled)
  unsigned short* Wz2 =(unsigned short*)p; p+=(size_t)H_*H_*2;         // 0.5 MiB
  unsigned short* Wp  =(unsigned short*)p; p+=(size_t)1024*H_*2;       // 1 MiB
  float* biasp        =(float*)p;          p+=1024*4;
  float* stats        =(float*)p;          p+=3*1024*4;                // [sum|sumsq] x 3 layers

  k_zero<<<12,256,0,stream>>>((unsigned int*)stats, 3*1024);
  k_swz<<<H_*H_/256,256,0,stream>>>(WhK1, Wz1);
  k_swz<<<H_*H_/256,256,0,stream>>>(WhK2, Wz2);

  // ---- layer 1 (BN stats fused into recurrence) ----
  for(int c=0;c<NC_;++c){
    k_proj1<<<B_,256,0,stream>>>(x,inlng,inlnb,WxK1,bxK1,Wxz1,bxz1,xK,z,c*TC_);
    k_recur9<<<64,512,0,stream>>>(xK,z,Wz1,bhK1,o,hbuf,stats,c*TC_);
  }

  // ---- layer 2 (BN1 folded into proj weights) ----
  k_foldw<<<1024*H_/256,256,0,stream>>>(WxK2,Wxz2,stats,bn1g,Wp);
  k_foldb<<<256,256,0,stream>>>(WxK2,Wxz2,stats,bn1g,bn1b,bxK2,bxz2,biasp);
  dim3 g23(B_/4, 8);
  for(int c=0;c<NC_;++c){
    k_proj23<<<g23,256,0,stream>>>(o,Wp,biasp,xK,z,c*TC_);
    k_recur9<<<64,512,0,stream>>>(xK,z,Wz2,bhK2,o,hbuf,stats+1024,c*TC_);
  }

  // ---- layer 3 (shared weights, BN2 folded) ----
  k_foldw<<<1024*H_/256,256,0,stream>>>(WxK2,Wxz2,stats+1024,bn2g,Wp);
  k_foldb<<<256,256,0,stream>>>(WxK2,Wxz2,stats+1024,bn2g,bn2b,bxK2,bxz2,biasp);
  for(int c=0;c<NC_;++c){
    k_proj23<<<g23,256,0,stream>>>(o,Wp,biasp,xK,z,c*TC_);
    k_recur9<<<64,512,0,stream>>>(xK,z,Wz2,bhK2,o,hbuf,stats+2048,c*TC_);
  }

  // ---- head ----
  k_head<<<B_,512,0,stream>>>(o, stats+2048, bn2g,bn2b, clng,clnb, Wc,bc, out);
}

// Round 13
// 3772.479 us; speedup vs baseline: 1.1542x; 1.1542x over previous
//
#include <hip/hip_runtime.h>
#include <hip/hip_bf16.h>
#include <math.h>

#define B_ 1024
#define T_ 128
#define D_ 13
#define H_ 512
#define C_ 9
#define TC_ 32              /* time chunk */
#define NC_ (T_/TC_)        /* 4 chunks */
#define NT_ (B_*T_)         /* 131072 */
#define EPS 1e-5f
#define WPAD 520            /* padded hbd row stride (shorts): 1040B -> 4-bank shift/row */

using frag_ab = __attribute__((ext_vector_type(8))) short;   // 8 bf16 (4 VGPRs)
using frag_cd = __attribute__((ext_vector_type(4))) float;   // 4 fp32
typedef unsigned short ushort8 __attribute__((ext_vector_type(8)));

static __device__ __forceinline__ float bf2f(unsigned short u){
  union { unsigned int i; float f; } v; v.i = ((unsigned int)u)<<16; return v.f;
}
static __device__ __forceinline__ unsigned short f2bf(float f){
  union { float f; unsigned int i; } v; v.f = f;
  unsigned int r = v.i + 0x7FFF + ((v.i >> 16) & 1);   // round-to-nearest-even
  return (unsigned short)(r >> 16);
}
static __device__ __forceinline__ float sigmoidf_(float x){ return 1.0f/(1.0f+__expf(-x)); }
static __device__ __forceinline__ float tanhf_(float x){
  return 1.0f - 2.0f/(__expf(2.0f*x)+1.0f);   // saturates via exp over/underflow
}

__global__ void k_zero(unsigned int* __restrict__ p, int n){
  int i=blockIdx.x*256+threadIdx.x; if(i<n) p[i]=0u;
}

// ---- swizzle WhK (fp32 512x512) into per-(64-col-slice) contiguous MFMA B-fragment stream ----
__global__ void k_swz(const float* __restrict__ Wf, unsigned short* __restrict__ Wz){
  int dst = blockIdx.x*256 + threadIdx.x;   // over 512*512
  int w = dst >> 15;
  int i = (dst >> 9) & 63;
  int L = (dst >> 3) & 63;
  int e = dst & 7;
  int kc = i >> 2, c = i & 3;
  int row = w*64 + c*16 + (L & 15);
  int col = kc*32 + ((L >> 4) << 3) + e;
  Wz[dst] = f2bf(Wf[row*H_ + col]);
}

// ---------------- input LN + layer-1 projections (K=13, VALU), one chunk (solo) ----------------
__global__ __launch_bounds__(256) void k_proj1(
    const float* __restrict__ x, const float* __restrict__ g, const float* __restrict__ bvec,
    const float* __restrict__ WxK, const float* __restrict__ bxK,
    const float* __restrict__ Wxz, const float* __restrict__ bxz,
    unsigned short* __restrict__ xKo, unsigned short* __restrict__ zo, int t0)
{
  __shared__ float wK[H_*D_];
  __shared__ float wz[H_*D_];
  __shared__ float xn[TC_][D_];
  int tid = threadIdx.x;
  int b = blockIdx.x;
  const float* xin = x + ((size_t)b*T_ + t0)*D_;
  for(int i=tid;i<H_*D_;i+=256){ wK[i]=WxK[i]; wz[i]=Wxz[i]; }
  for(int i=tid;i<TC_*D_;i+=256){ ((float*)xn)[i] = xin[i]; }
  __syncthreads();
  if(tid<TC_){
    float m=0.f; for(int d=0;d<D_;++d) m+=xn[tid][d]; m*=(1.0f/D_);
    float v=0.f; for(int d=0;d<D_;++d){float t=xn[tid][d]-m; v+=t*t;} v*=(1.0f/D_);
    float inv = rsqrtf(v+EPS);
    for(int d=0;d<D_;++d) xn[tid][d] = (xn[tid][d]-m)*inv*g[d]+bvec[d];
  }
  __syncthreads();
  size_t ob = (size_t)b*TC_*H_;
  for(int hh=0; hh<2; ++hh){
    int h = tid + hh*256;
    float bK = bxK[h], bz = bxz[h];
    for(int r=0;r<TC_;++r){
      float aK=bK, az=bz;
      #pragma unroll
      for(int d=0;d<D_;++d){ float xv = xn[r][d]; aK += xv*wK[h*D_+d]; az += xv*wz[h*D_+d]; }
      xKo[ob + (size_t)r*H_ + h] = f2bf(aK);
      zo [ob + (size_t)r*H_ + h] = f2bf(tanhf_(az));
    }
  }
}

// ---- recurrence (r11 body, standalone fallback): 16 waves, 32 cols/wave, ONE barrier/step ----
__global__ __launch_bounds__(1024,1) void k_recur8(
    const unsigned short* __restrict__ xK, const unsigned short* __restrict__ z,
    const unsigned short* __restrict__ Wz, const float* __restrict__ bhK,
    unsigned short* __restrict__ o, float* __restrict__ hbuf,
    float* __restrict__ stats, int t0)
{
  __shared__ __align__(16) unsigned short Wl[8*15*512];
  __shared__ __align__(16) unsigned short hbd[2][16*WPAD];
  int tid=threadIdx.x, lane=tid&63, w=tid>>6;
  int ow=w>>1, oh=w&1;
  int q=lane>>4, cl=lane&15;
  int b0 = blockIdx.x*16;
  const unsigned short* wb = Wz + ((size_t)ow<<15);
  const unsigned short* wl = Wl + ow*7680;
  for(int j=tid;j<7680;j+=1024){
    int wv = j/960, off8 = j%960;
    *(ushort8*)&Wl[wv*7680 + off8*8] = *(const ushort8*)&Wz[((size_t)wv<<15) + off8*8];
  }
  float hp[8]; float bh[2]; int col[2];
  float ss[2]={0.f,0.f}, qq[2]={0.f,0.f};
  #pragma unroll
  for(int c=0;c<2;++c){ col[c]=ow*64 + (oh*2+c)*16 + cl; bh[c]=bhK[col[c]]; }
  if(t0==0){
    for(int i=tid;i<16*WPAD;i+=1024) hbd[0][i]=0;
    #pragma unroll
    for(int i=0;i<8;++i) hp[i]=0.f;
  } else {
    for(int i=tid;i<16*H_;i+=1024){ int r=i>>9,c=i&511; hbd[0][r*WPAD+c]=f2bf(hbuf[(size_t)(b0+r)*H_+c]); }
    #pragma unroll
    for(int c=0;c<2;++c)
      #pragma unroll
      for(int rg=0;rg<4;++rg) hp[c*4+rg]=hbuf[(size_t)(b0+q*4+rg)*H_+col[c]];
  }
  __syncthreads();
  for(int dt=0;dt<TC_;++dt){
    int cb = dt&1, nb = cb^1;
    float ga[8], za[8];
    #pragma unroll
    for(int c=0;c<2;++c)
      #pragma unroll
      for(int rg=0;rg<4;++rg){
        size_t gi = ((size_t)(b0+q*4+rg)*TC_ + dt)*H_ + col[c];
        ga[c*4+rg]=bf2f(xK[gi]); za[c*4+rg]=bf2f(z[gi]);
      }
    frag_cd acc[2] = {};
    #pragma unroll
    for(int kc=0;kc<16;++kc){
      frag_ab af = *(const frag_ab*)&hbd[cb][cl*WPAD + kc*32 + q*8];
      #pragma unroll
      for(int c=0;c<2;++c){
        int f = kc*4 + oh*2 + c;
        frag_ab bf = (f<15) ? *(const frag_ab*)&wl[f*512 + lane*8]
                            : *(const frag_ab*)&wb[f*512 + lane*8];
        acc[c] = __builtin_amdgcn_mfma_f32_16x16x32_bf16(af, bf, acc[c], 0,0,0);
      }
    }
    unsigned short hnb[8];
    #pragma unroll
    for(int c=0;c<2;++c){
      #pragma unroll
      for(int rg=0;rg<4;++rg){
        int idx = c*4+rg;
        float gv = acc[c][rg] + bh[c] + ga[idx];
        float K  = sigmoidf_(gv);
        float hn = tanhf_(K*hp[idx] + (1.f-K)*za[idx]);
        hp[idx]=hn;
        hnb[idx]=f2bf(hn);
        hbd[nb][(q*4+rg)*WPAD + col[c]] = hnb[idx];
        float hf = bf2f(hnb[idx]);
        ss[c] += hf; qq[c] += hf*hf;
      }
    }
    __syncthreads();
    #pragma unroll
    for(int c=0;c<2;++c)
      #pragma unroll
      for(int rg=0;rg<4;++rg)
        o[((size_t)(b0+q*4+rg)*T_ + t0+dt)*H_ + col[c]] = hnb[c*4+rg];
  }
  #pragma unroll
  for(int c=0;c<2;++c)
    #pragma unroll
    for(int rg=0;rg<4;++rg) hbuf[(size_t)(b0+q*4+rg)*H_+col[c]] = hp[c*4+rg];
  #pragma unroll
  for(int c=0;c<2;++c){
    float s=ss[c], sq=qq[c];
    s  += __shfl_xor(s,16,64);  s  += __shfl_xor(s,32,64);
    sq += __shfl_xor(sq,16,64); sq += __shfl_xor(sq,32,64);
    if(q==0){ atomicAdd(&stats[col[c]], s); atomicAdd(&stats[H_+col[c]], sq); }
  }
}

// ---- FUSED: blocks 0..63 = recurrence chunk t0r (r11 body, verbatim); blocks 64.. =
// proj for chunk t0p (projKind: 1=proj1/LN, 2=proj23, 0=none). Data-disjoint: recur
// writes o chunk-t0r rows and reads xKr/zr; proj reads o chunk-t0p rows (prev layer) /
// input x and writes the OTHER xK/z buffer. No inter-block sync; any schedule correct.
__global__ __launch_bounds__(1024,1) void k_fused(
    const unsigned short* __restrict__ xKr, const unsigned short* __restrict__ zr,
    const unsigned short* __restrict__ Wz, const float* __restrict__ bhK,
    unsigned short* __restrict__ o, float* __restrict__ hbuf,
    float* __restrict__ stats, int t0r,
    int projKind,
    const unsigned short* __restrict__ Wp, const float* __restrict__ biasp,
    const float* __restrict__ x, const float* __restrict__ lng, const float* __restrict__ lnb,
    const float* __restrict__ WxK, const float* __restrict__ bxK,
    const float* __restrict__ Wxz, const float* __restrict__ bxz,
    unsigned short* __restrict__ xKo, unsigned short* __restrict__ zo, int t0p)
{
  __shared__ __align__(16) unsigned char LDSB[156160];
  int tid=threadIdx.x;
  if(blockIdx.x < 64){
    // ================= recurrence (verbatim r11) =================
    unsigned short* Wl  = (unsigned short*)LDSB;            // 122880 B
    unsigned short* hbd = (unsigned short*)(LDSB + 122880); // 2*16*WPAD shorts
    int lane=tid&63, w=tid>>6;
    int ow=w>>1, oh=w&1;
    int q=lane>>4, cl=lane&15;
    int b0 = blockIdx.x*16;
    const unsigned short* wb = Wz + ((size_t)ow<<15);
    const unsigned short* wl = Wl + ow*7680;
    for(int j=tid;j<7680;j+=1024){
      int wv = j/960, off8 = j%960;
      *(ushort8*)&Wl[wv*7680 + off8*8] = *(const ushort8*)&Wz[((size_t)wv<<15) + off8*8];
    }
    float hp[8]; float bh[2]; int col[2];
    float ss[2]={0.f,0.f}, qq[2]={0.f,0.f};
    #pragma unroll
    for(int c=0;c<2;++c){ col[c]=ow*64 + (oh*2+c)*16 + cl; bh[c]=bhK[col[c]]; }
    if(t0r==0){
      for(int i=tid;i<16*WPAD;i+=1024) hbd[i]=0;
      #pragma unroll
      for(int i=0;i<8;++i) hp[i]=0.f;
    } else {
      for(int i=tid;i<16*H_;i+=1024){ int r=i>>9,c=i&511; hbd[r*WPAD+c]=f2bf(hbuf[(size_t)(b0+r)*H_+c]); }
      #pragma unroll
      for(int c=0;c<2;++c)
        #pragma unroll
        for(int rg=0;rg<4;++rg) hp[c*4+rg]=hbuf[(size_t)(b0+q*4+rg)*H_+col[c]];
    }
    __syncthreads();
    for(int dt=0;dt<TC_;++dt){
      int cb = dt&1, nb = cb^1;
      float ga[8], za[8];
      #pragma unroll
      for(int c=0;c<2;++c)
        #pragma unroll
        for(int rg=0;rg<4;++rg){
          size_t gi = ((size_t)(b0+q*4+rg)*TC_ + dt)*H_ + col[c];
          ga[c*4+rg]=bf2f(xKr[gi]); za[c*4+rg]=bf2f(zr[gi]);
        }
      frag_cd acc[2] = {};
      #pragma unroll
      for(int kc=0;kc<16;++kc){
        frag_ab af = *(const frag_ab*)&hbd[cb*16*WPAD + cl*WPAD + kc*32 + q*8];
        #pragma unroll
        for(int c=0;c<2;++c){
          int f = kc*4 + oh*2 + c;
          frag_ab bf = (f<15) ? *(const frag_ab*)&wl[f*512 + lane*8]
                              : *(const frag_ab*)&wb[f*512 + lane*8];
          acc[c] = __builtin_amdgcn_mfma_f32_16x16x32_bf16(af, bf, acc[c], 0,0,0);
        }
      }
      unsigned short hnb[8];
      #pragma unroll
      for(int c=0;c<2;++c){
        #pragma unroll
        for(int rg=0;rg<4;++rg){
          int idx = c*4+rg;
          float gv = acc[c][rg] + bh[c] + ga[idx];
          float K  = sigmoidf_(gv);
          float hn = tanhf_(K*hp[idx] + (1.f-K)*za[idx]);
          hp[idx]=hn;
          hnb[idx]=f2bf(hn);
          hbd[nb*16*WPAD + (q*4+rg)*WPAD + col[c]] = hnb[idx];
          float hf = bf2f(hnb[idx]);
          ss[c] += hf; qq[c] += hf*hf;
        }
      }
      __syncthreads();
      #pragma unroll
      for(int c=0;c<2;++c)
        #pragma unroll
        for(int rg=0;rg<4;++rg)
          o[((size_t)(b0+q*4+rg)*T_ + t0r+dt)*H_ + col[c]] = hnb[c*4+rg];
    }
    #pragma unroll
    for(int c=0;c<2;++c)
      #pragma unroll
      for(int rg=0;rg<4;++rg) hbuf[(size_t)(b0+q*4+rg)*H_+col[c]] = hp[c*4+rg];
    #pragma unroll
    for(int c=0;c<2;++c){
      float s=ss[c], sq=qq[c];
      s  += __shfl_xor(s,16,64);  s  += __shfl_xor(s,32,64);
      sq += __shfl_xor(sq,16,64); sq += __shfl_xor(sq,32,64);
      if(q==0){ atomicAdd(&stats[col[c]], s); atomicAdd(&stats[H_+col[c]], sq); }
    }
  } else if(projKind == 2){
    // ================= proj23 for chunk t0p: 4 sub-engines x 256 thr =================
    int s = tid>>8, stid = tid&255;
    unsigned short* As = (unsigned short*)(LDSB + s*16384);        // 8KB
    unsigned short* Bs = (unsigned short*)(LDSB + s*16384 + 8192); // 8KB
    int lane=stid&63, w4=stid>>6;
    int q=lane>>4, cl=lane&15;
    int eng = (int)(blockIdx.x-64)*4 + s;   // 0..767
    for(int it=0; it<3; ++it){
      int tile = eng + it*768;
      bool valid = tile < 2048;
      int vt = valid ? tile : 0;
      int mt = vt>>3, ntl = vt&7;
      int b0p = mt*4, n0 = ntl*128;
      int wm = (w4>>1)*64, wn=(w4&1)*64;
      frag_cd acc[4][4] = {};
      int sr = stid>>1, cb2 = (stid&1)*16;
      size_t arow = ((size_t)(b0p + (sr>>5))*T_ + t0p + (sr&31))*H_;
      size_t brow = (size_t)(n0+sr)*H_;
      for(int k0=0;k0<H_;k0+=32){
        *(frag_ab*)&As[sr*32+cb2]   = *(const frag_ab*)&o [arow + k0+cb2];
        *(frag_ab*)&As[sr*32+cb2+8] = *(const frag_ab*)&o [arow + k0+cb2+8];
        *(frag_ab*)&Bs[sr*32+cb2]   = *(const frag_ab*)&Wp[brow + k0+cb2];
        *(frag_ab*)&Bs[sr*32+cb2+8] = *(const frag_ab*)&Wp[brow + k0+cb2+8];
        __syncthreads();
        frag_ab af[4], bfr[4];
        #pragma unroll
        for(int mi=0;mi<4;++mi) af[mi]  = *(const frag_ab*)&As[(wm+mi*16+cl)*32 + q*8];
        #pragma unroll
        for(int ni=0;ni<4;++ni) bfr[ni] = *(const frag_ab*)&Bs[(wn+ni*16+cl)*32 + q*8];
        #pragma unroll
        for(int mi=0;mi<4;++mi)
          #pragma unroll
          for(int ni=0;ni<4;++ni)
            acc[mi][ni] = __builtin_amdgcn_mfma_f32_16x16x32_bf16(af[mi], bfr[ni], acc[mi][ni],0,0,0);
        __syncthreads();
      }
      if(valid){
        #pragma unroll
        for(int ni=0;ni<4;++ni){
          int coln = n0+wn+ni*16+cl;
          float bp = biasp[coln];
          bool isz = coln>=H_;
          #pragma unroll
          for(int mi=0;mi<4;++mi){
            #pragma unroll
            for(int rg=0;rg<4;++rg){
              int rm = wm+mi*16+q*4+rg;
              size_t orow = (size_t)(b0p*TC_ + rm)*H_;
              float v = acc[mi][ni][rg] + bp;
              if(isz) zo [orow + coln-H_] = f2bf(tanhf_(v));
              else    xKo[orow + coln]    = f2bf(v);
            }
          }
        }
      }
    }
  } else if(projKind == 1){
    // ================= proj1 (LN + K=13 proj) for chunk t0p =================
    float* wKs = (float*)LDSB;                  // 26624 B
    float* wzs = (float*)(LDSB + 26624);        // 26624 B
    int s = tid>>8, stid = tid&255;
    float* xns = (float*)(LDSB + 53248 + s*1664);  // 32x13 floats per sub-engine
    for(int i=tid;i<H_*D_;i+=1024){ wKs[i]=WxK[i]; wzs[i]=Wxz[i]; }
    __syncthreads();
    int eng = (int)(blockIdx.x-64)*4 + s;   // 0..767
    for(int it=0; it<2; ++it){
      int row = eng + it*768;
      bool valid = row < B_;
      int b = valid ? row : 0;
      const float* xin = x + ((size_t)b*T_ + t0p)*D_;
      for(int i=stid;i<TC_*D_;i+=256) xns[i] = xin[i];
      __syncthreads();
      if(stid<TC_){
        float m=0.f; for(int d=0;d<D_;++d) m+=xns[stid*D_+d]; m*=(1.0f/D_);
        float v=0.f; for(int d=0;d<D_;++d){float t=xns[stid*D_+d]-m; v+=t*t;} v*=(1.0f/D_);
        float inv = rsqrtf(v+EPS);
        for(int d=0;d<D_;++d) xns[stid*D_+d] = (xns[stid*D_+d]-m)*inv*lng[d]+lnb[d];
      }
      __syncthreads();
      size_t ob = (size_t)b*TC_*H_;
      for(int hh=0; hh<2; ++hh){
        int h = stid + hh*256;
        float bK = bxK[h], bz = bxz[h];
        for(int r=0;r<TC_;++r){
          float aK=bK, az=bz;
          #pragma unroll
          for(int d=0;d<D_;++d){ float xv = xns[r*D_+d]; aK += xv*wKs[h*D_+d]; az += xv*wzs[h*D_+d]; }
          if(valid){
            xKo[ob + (size_t)r*H_ + h] = f2bf(aK);
            zo [ob + (size_t)r*H_ + h] = f2bf(tanhf_(az));
          }
        }
      }
      __syncthreads();   // before next iteration overwrites xns
    }
  }
}

// ---------------- fold BN into projection weights / bias ----------------
__global__ void k_foldw(const float* __restrict__ WxK, const float* __restrict__ Wxz,
                        const float* __restrict__ stats, const float* __restrict__ bng,
                        unsigned short* __restrict__ Wp){
  int i = blockIdx.x*256+threadIdx.x;           // over 1024*512
  int n = i>>9, k = i&511;
  float mean = stats[k]*(1.f/NT_);
  float var  = stats[H_+k]*(1.f/NT_) - mean*mean;
  float s = bng[k]*rsqrtf(var+EPS);
  float wv = (n<H_) ? WxK[(size_t)n*H_+k] : Wxz[(size_t)(n-H_)*H_+k];
  Wp[i] = f2bf(wv*s);
}

__global__ __launch_bounds__(256) void k_foldb(const float* __restrict__ WxK, const float* __restrict__ Wxz,
                        const float* __restrict__ stats, const float* __restrict__ bng, const float* __restrict__ bnb,
                        const float* __restrict__ bxK, const float* __restrict__ bxz,
                        float* __restrict__ biasp){
  int w = threadIdx.x>>6, lane=threadIdx.x&63;
  int n = blockIdx.x*4 + w;
  const float* W = (n<H_) ? &WxK[(size_t)n*H_] : &Wxz[(size_t)(n-H_)*H_];
  float base = (n<H_) ? bxK[n] : bxz[n-H_];
  float acc=0.f;
  for(int k=lane;k<H_;k+=64){
    float mean = stats[k]*(1.f/NT_);
    float var  = stats[H_+k]*(1.f/NT_)-mean*mean;
    float s = bng[k]*rsqrtf(var+EPS);
    float t = bnb[k]-mean*s;
    acc += t*W[k];
  }
  for(int off=32;off;off>>=1) acc += __shfl_down(acc, off, 64);
  if(lane==0) biasp[n] = base + acc;
}

// ------- solo proj23 (chunk c0 of each layer) -------
__global__ __launch_bounds__(256) void k_proj23(
    const unsigned short* __restrict__ A,
    const unsigned short* __restrict__ Wp,
    const float* __restrict__ biasp,
    unsigned short* __restrict__ xKo, unsigned short* __restrict__ zo, int t0)
{
  __shared__ __align__(16) unsigned short As[128*32];
  __shared__ __align__(16) unsigned short Bs[128*32];
  int tid=threadIdx.x, lane=tid&63, w=tid>>6;
  int q=lane>>4, cl=lane&15;
  int b0p = blockIdx.x*4;
  int n0 = blockIdx.y*128;
  int wm = (w>>1)*64, wn=(w&1)*64;
  frag_cd acc[4][4] = {};
  int sr = tid>>1, cb = (tid&1)*16;
  size_t arow = ((size_t)(b0p + (sr>>5))*T_ + t0 + (sr&31))*H_;
  size_t brow = (size_t)(n0+sr)*H_;
  for(int k0=0;k0<H_;k0+=32){
    *(frag_ab*)&As[sr*32+cb]   = *(const frag_ab*)&A [arow + k0+cb];
    *(frag_ab*)&As[sr*32+cb+8] = *(const frag_ab*)&A [arow + k0+cb+8];
    *(frag_ab*)&Bs[sr*32+cb]   = *(const frag_ab*)&Wp[brow + k0+cb];
    *(frag_ab*)&Bs[sr*32+cb+8] = *(const frag_ab*)&Wp[brow + k0+cb+8];
    __syncthreads();
    frag_ab af[4], bfr[4];
    #pragma unroll
    for(int mt=0;mt<4;++mt) af[mt]  = *(const frag_ab*)&As[(wm+mt*16+cl)*32 + q*8];
    #pragma unroll
    for(int nt=0;nt<4;++nt) bfr[nt] = *(const frag_ab*)&Bs[(wn+nt*16+cl)*32 + q*8];
    #pragma unroll
    for(int mt=0;mt<4;++mt)
      #pragma unroll
      for(int nt=0;nt<4;++nt)
        acc[mt][nt] = __builtin_amdgcn_mfma_f32_16x16x32_bf16(af[mt], bfr[nt], acc[mt][nt],0,0,0);
    __syncthreads();
  }
  #pragma unroll
  for(int nt=0;nt<4;++nt){
    int coln = n0+wn+nt*16+cl;
    float bp = biasp[coln];
    bool isz = coln>=H_;
    #pragma unroll
    for(int mt=0;mt<4;++mt){
      #pragma unroll
      for(int rg=0;rg<4;++rg){
        int rm = wm+mt*16+q*4+rg;
        size_t orow = (size_t)(b0p*TC_ + rm)*H_;
        float v = acc[mt][nt][rg] + bp;
        if(isz) zo [orow + coln-H_] = f2bf(tanhf_(v));
        else    xKo[orow + coln]    = f2bf(v);
      }
    }
  }
}

// ---------------- head: BN3 + LN + 512->9 GEMV + log_softmax ----------------
__global__ __launch_bounds__(512) void k_head(const unsigned short* __restrict__ o,
     const float* __restrict__ stats, const float* __restrict__ bng, const float* __restrict__ bnb,
     const float* __restrict__ clng, const float* __restrict__ clnb,
     const float* __restrict__ Wc, const float* __restrict__ bc, float* __restrict__ out)
{
  __shared__ float red[8];
  __shared__ float lred[8][9];
  int tid=threadIdx.x, lane=tid&63, w=tid>>6;
  int b = blockIdx.x;
  int c = tid;
  float v = bf2f(o[((size_t)b*T_ + (T_-1))*H_ + c]);
  float mean = stats[c]*(1.f/NT_), var = stats[H_+c]*(1.f/NT_)-mean*mean;
  float s = bng[c]*rsqrtf(var+EPS);
  float y = v*s + (bnb[c]-mean*s);
  float sm=y;
  for(int off=32;off;off>>=1) sm+=__shfl_down(sm,off,64);
  if(lane==0) red[w]=sm;
  __syncthreads();
  float mu=0.f; for(int i=0;i<8;++i) mu+=red[i]; mu*=(1.f/H_);
  float d = y-mu;
  float vq = d*d;
  for(int off=32;off;off>>=1) vq+=__shfl_down(vq,off,64);
  __syncthreads();
  if(lane==0) red[w]=vq;
  __syncthreads();
  float vv=0.f; for(int i=0;i<8;++i) vv+=red[i]; vv*=(1.f/H_);
  float yn = d*rsqrtf(vv+EPS)*clng[c]+clnb[c];
  for(int cls=0;cls<C_;++cls){
    float t = yn*Wc[(size_t)cls*H_+c];
    for(int off=32;off;off>>=1) t+=__shfl_down(t,off,64);
    if(lane==0) lred[w][cls]=t;
  }
  __syncthreads();
  if(tid==0){
    float lg[C_]; float mx=-1e30f;
    for(int cls=0;cls<C_;++cls){
      float t=bc[cls]; for(int i=0;i<8;++i) t+=lred[i][cls];
      lg[cls]=t; mx=fmaxf(mx,t);
    }
    float se=0.f; for(int cls=0;cls<C_;++cls) se+=__expf(lg[cls]-mx);
    float lse=mx+logf(se);
    for(int cls=0;cls<C_;++cls) out[(size_t)b*C_+cls]=lg[cls]-lse;
  }
}

extern "C" void kernel_launch(void* const* d_in, const int* in_sizes, int n_in,
                              void* d_out, int out_size, void* d_ws, size_t ws_size,
                              hipStream_t stream)
{
  (void)in_sizes; (void)n_in; (void)out_size;
  const float* x    =(const float*)d_in[0];
  const float* inlng=(const float*)d_in[1];
  const float* inlnb=(const float*)d_in[2];
  const float* WxK1 =(const float*)d_in[3];
  const float* bxK1 =(const float*)d_in[4];
  const float* Wxz1 =(const float*)d_in[5];
  const float* bxz1 =(const float*)d_in[6];
  const float* WhK1 =(const float*)d_in[7];
  const float* bhK1 =(const float*)d_in[8];
  const float* bn1g =(const float*)d_in[9];
  const float* bn1b =(const float*)d_in[10];
  const float* WxK2 =(const float*)d_in[11];
  const float* bxK2 =(const float*)d_in[12];
  const float* Wxz2 =(const float*)d_in[13];
  const float* bxz2 =(const float*)d_in[14];
  const float* WhK2 =(const float*)d_in[15];
  const float* bhK2 =(const float*)d_in[16];
  const float* bn2g =(const float*)d_in[17];
  const float* bn2b =(const float*)d_in[18];
  const float* clng =(const float*)d_in[19];
  const float* clnb =(const float*)d_in[20];
  const float* Wc   =(const float*)d_in[21];
  const float* bc   =(const float*)d_in[22];
  float* out=(float*)d_out;

  const size_t NEED_FUSED = 272646144ull;   // ~260 MiB (double xK/z buffers)
  bool fused = ws_size >= NEED_FUSED;

  char* p=(char*)d_ws;
  unsigned short* o = (unsigned short*)p; p+=(size_t)NT_*H_*2;          // 128 MiB
  unsigned short* xKb[2]; unsigned short* zb[2];
  xKb[0]=(unsigned short*)p; p+=(size_t)B_*TC_*H_*2;                    // 32 MiB
  zb[0] =(unsigned short*)p; p+=(size_t)B_*TC_*H_*2;                    // 32 MiB
  if(fused){
    xKb[1]=(unsigned short*)p; p+=(size_t)B_*TC_*H_*2;                  // 32 MiB
    zb[1] =(unsigned short*)p; p+=(size_t)B_*TC_*H_*2;                  // 32 MiB
  } else { xKb[1]=xKb[0]; zb[1]=zb[0]; }
  float* hbuf         =(float*)p;          p+=(size_t)B_*H_*4;          // 2 MiB
  unsigned short* Wz1 =(unsigned short*)p; p+=(size_t)H_*H_*2;
  unsigned short* Wz2 =(unsigned short*)p; p+=(size_t)H_*H_*2;
  unsigned short* Wp  =(unsigned short*)p; p+=(size_t)1024*H_*2;
  float* biasp        =(float*)p;          p+=1024*4;
  float* stats        =(float*)p;          p+=3*1024*4;

  k_zero<<<12,256,0,stream>>>((unsigned int*)stats, 3*1024);
  k_swz<<<H_*H_/256,256,0,stream>>>(WhK1, Wz1);
  k_swz<<<H_*H_/256,256,0,stream>>>(WhK2, Wz2);

  dim3 g23(B_/4, 8);
  if(fused){
    // ---- layer 1 ----
    k_proj1<<<B_,256,0,stream>>>(x,inlng,inlnb,WxK1,bxK1,Wxz1,bxz1,xKb[0],zb[0],0);
    for(int k=0;k<NC_;++k){
      int kind = (k<NC_-1) ? 1 : 0;
      int grid = 64 + (kind?192:0);
      k_fused<<<grid,1024,0,stream>>>(xKb[k&1],zb[k&1],Wz1,bhK1,o,hbuf,stats,k*TC_,
          kind, Wp,biasp, x,inlng,inlnb, WxK1,bxK1,Wxz1,bxz1,
          xKb[(k+1)&1],zb[(k+1)&1],(k+1)*TC_);
    }
    // ---- layer 2 ----
    k_foldw<<<1024*H_/256,256,0,stream>>>(WxK2,Wxz2,stats,bn1g,Wp);
    k_foldb<<<256,256,0,stream>>>(WxK2,Wxz2,stats,bn1g,bn1b,bxK2,bxz2,biasp);
    k_proj23<<<g23,256,0,stream>>>(o,Wp,biasp,xKb[0],zb[0],0);
    for(int k=0;k<NC_;++k){
      int kind = (k<NC_-1) ? 2 : 0;
      int grid = 64 + (kind?192:0);
      k_fused<<<grid,1024,0,stream>>>(xKb[k&1],zb[k&1],Wz2,bhK2,o,hbuf,stats+1024,k*TC_,
          kind, Wp,biasp, x,inlng,inlnb, WxK1,bxK1,Wxz1,bxz1,
          xKb[(k+1)&1],zb[(k+1)&1],(k+1)*TC_);
    }
    // ---- layer 3 ----
    k_foldw<<<1024*H_/256,256,0,stream>>>(WxK2,Wxz2,stats+1024,bn2g,Wp);
    k_foldb<<<256,256,0,stream>>>(WxK2,Wxz2,stats+1024,bn2g,bn2b,bxK2,bxz2,biasp);
    k_proj23<<<g23,256,0,stream>>>(o,Wp,biasp,xKb[0],zb[0],0);
    for(int k=0;k<NC_;++k){
      int kind = (k<NC_-1) ? 2 : 0;
      int grid = 64 + (kind?192:0);
      k_fused<<<grid,1024,0,stream>>>(xKb[k&1],zb[k&1],Wz2,bhK2,o,hbuf,stats+2048,k*TC_,
          kind, Wp,biasp, x,inlng,inlnb, WxK1,bxK1,Wxz1,bxz1,
          xKb[(k+1)&1],zb[(k+1)&1],(k+1)*TC_);
    }
  } else {
    // ---- fallback: exact r11 sequence, single buffers ----
    for(int c=0;c<NC_;++c){
      k_proj1<<<B_,256,0,stream>>>(x,inlng,inlnb,WxK1,bxK1,Wxz1,bxz1,xKb[0],zb[0],c*TC_);
      k_recur8<<<64,1024,0,stream>>>(xKb[0],zb[0],Wz1,bhK1,o,hbuf,stats,c*TC_);
    }
    k_foldw<<<1024*H_/256,256,0,stream>>>(WxK2,Wxz2,stats,bn1g,Wp);
    k_foldb<<<256,256,0,stream>>>(WxK2,Wxz2,stats,bn1g,bn1b,bxK2,bxz2,biasp);
    for(int c=0;c<NC_;++c){
      k_proj23<<<g23,256,0,stream>>>(o,Wp,biasp,xKb[0],zb[0],c*TC_);
      k_recur8<<<64,1024,0,stream>>>(xKb[0],zb[0],Wz2,bhK2,o,hbuf,stats+1024,c*TC_);
    }
    k_foldw<<<1024*H_/256,256,0,stream>>>(WxK2,Wxz2,stats+1024,bn2g,Wp);
    k_foldb<<<256,256,0,stream>>>(WxK2,Wxz2,stats+1024,bn2g,bn2b,bxK2,bxz2,biasp);
    for(int c=0;c<NC_;++c){
      k_proj23<<<g23,256,0,stream>>>(o,Wp,biasp,xKb[0],zb[0],c*TC_);
      k_recur8<<<64,1024,0,stream>>>(xKb[0],zb[0],Wz2,bhK2,o,hbuf,stats+2048,c*TC_);
    }
  }

  // ---- head ----
  k_head<<<B_,512,0,stream>>>(o, stats+2048, bn2g,bn2b, clng,clnb, Wc,bc, out);
}